// Round 1
// baseline (224.600 us; speedup 1.0000x reference)
//
#include <hip/hip_runtime.h>
#include <math.h>

#define B_ 2
#define C_ 32
#define D_ 32
#define H_ 32
#define W_ 64
#define HW_ (H_*W_)         // 2048
#define DHW_ (D_*H_*W_)     // 65536
#define CDHW_ (C_*DHW_)     // 2097152
#define NSP_ DHW_           // spatial points per batch
#define BN_N_ (B_*DHW_)     // 131072
#define ACC_OFF 16777216    // byte offset of double accumulators in ws (after M)
#define NEG_INF_F (-3.402823466e38f)
#define BORDER 1e-3

// acc double layout: [0..1] norm_sum[b], [2..3] norm_sumsq[b], [4..35] bn_sum[o], [36..67] bn_sumsq[o]

// ---------------- threshold stats: norm = sum_c |x - roll(x, half)| ----------------
__global__ __launch_bounds__(256) void k_norm(const float* __restrict__ x, double* __restrict__ acc) {
    int idx = blockIdx.x * 256 + threadIdx.x;          // 0..131071
    int b = idx >> 16;
    int p = idx & 65535;
    int d = p >> 11, h = (p >> 6) & 31, w = p & 63;
    int pf = ((d ^ 16) << 11) | ((h ^ 16) << 6) | (w ^ 32);   // (i - n/2) mod n == i ^ (n/2)
    const float* xb = x + (size_t)b * CDHW_;
    double s = 0.0;
#pragma unroll
    for (int c = 0; c < 32; ++c) {
        float a  = xb[c * DHW_ + p];
        float bb = xb[c * DHW_ + pf];
        s += fabs((double)a - (double)bb);
    }
    double s2 = s * s;
    for (int off = 32; off; off >>= 1) {
        s  += __shfl_down(s,  off, 64);
        s2 += __shfl_down(s2, off, 64);
    }
    __shared__ double ls[4], ls2[4];
    int wv = threadIdx.x >> 6, ln = threadIdx.x & 63;
    if (ln == 0) { ls[wv] = s; ls2[wv] = s2; }
    __syncthreads();
    if (threadIdx.x == 0) {
        double t  = ls[0] + ls[1] + ls[2] + ls[3];
        double t2 = ls2[0] + ls2[1] + ls2[2] + ls2[3];
        atomicAdd(&acc[0 + b], t);
        atomicAdd(&acc[2 + b], t2);
    }
}

__device__ __forceinline__ double get_thr(const double* __restrict__ acc, int b) {
    double sum = acc[b], sq = acc[2 + b];
    double n = (double)NSP_;
    double mean = sum / n;
    double var = (sq - sum * sum / n) / (n - 1.0);   // ddof=1
    if (var < 0.0) var = 0.0;
    return mean - sqrt(var);
}

// ---------------- axis pass along W: one wave per (b,d,h) line, lane = w ----------------
__global__ __launch_bounds__(256) void k_pass_w(const float* __restrict__ x, const double* __restrict__ acc,
                                                float* __restrict__ M) {
    int wv = blockIdx.x * 4 + (threadIdx.x >> 6);   // 0..2047 lines
    int ln = threadIdx.x & 63;
    int b = wv >> 10, d = (wv >> 5) & 31, h = wv & 31;
    double thr = get_thr(acc, b);
    const float* base = x + (size_t)b * CDHW_ + d * HW_ + h * W_ + ln;
    float col[32], nb[32], Mv[32];
#pragma unroll
    for (int c = 0; c < 32; ++c) col[c] = base[c * DHW_];
    bool sel0 = (0.0 < thr);                        // s = 0 shift: dist == 0 exactly
#pragma unroll
    for (int c = 0; c < 32; ++c) { nb[c] = col[c]; Mv[c] = sel0 ? col[c] : NEG_INF_F; }
    int src = (ln - 2) & 63;
    for (int si = 1; si < 32; ++si) {               // shift s = 2*si
#pragma unroll
        for (int c = 0; c < 32; ++c) nb[c] = __shfl(nb[c], src, 64);   // nb = x[w - 2*si]
        float d0 = 0.f, d1 = 0.f, d2 = 0.f, d3 = 0.f;
#pragma unroll
        for (int c = 0; c < 32; c += 4) {
            d0 += fabsf(col[c+0] - nb[c+0]);
            d1 += fabsf(col[c+1] - nb[c+1]);
            d2 += fabsf(col[c+2] - nb[c+2]);
            d3 += fabsf(col[c+3] - nb[c+3]);
        }
        float ds = (d0 + d1) + (d2 + d3);
        bool cmp;
        bool border = fabs((double)ds - thr) < BORDER;
        if (__ballot(border)) {                     // rare exact path, wave-uniform branch
            double d64 = 0.0;
#pragma unroll
            for (int c = 0; c < 32; ++c) d64 += fabs((double)col[c] - (double)nb[c]);
            cmp = d64 < thr;
        } else {
            cmp = ((double)ds < thr);
        }
#pragma unroll
        for (int c = 0; c < 32; ++c) Mv[c] = (cmp && nb[c] > Mv[c]) ? nb[c] : Mv[c];
    }
    float* mb = M + (size_t)b * CDHW_ + d * HW_ + h * W_ + ln;
#pragma unroll
    for (int c = 0; c < 32; ++c) mb[c * DHW_] = Mv[c];
}

// ---------------- axis pass along H: wave = 2 lines (w0, w0+1); lane = h*2 + wsub ----------------
__global__ __launch_bounds__(256) void k_pass_h(const float* __restrict__ x, const double* __restrict__ acc,
                                                float* __restrict__ M) {
    int wv = blockIdx.x * 4 + (threadIdx.x >> 6);   // 0..2047
    int ln = threadIdx.x & 63;
    int b = wv >> 10;
    int r = wv & 1023;
    int d = r >> 5;
    int w0 = (r & 31) * 2;
    int h = ln >> 1, wsub = ln & 1;
    double thr = get_thr(acc, b);
    size_t off = (size_t)b * CDHW_ + d * HW_ + h * W_ + w0 + wsub;
    const float* base = x + off;
    float* mbase = M + off;
    float col[32], nb[32], Mv[32];
#pragma unroll
    for (int c = 0; c < 32; ++c) col[c] = base[c * DHW_];
    bool sel0 = (0.0 < thr);
#pragma unroll
    for (int c = 0; c < 32; ++c) { nb[c] = col[c]; Mv[c] = sel0 ? col[c] : NEG_INF_F; }
    int src = (ln - 4) & 63;                        // rotate by 4 lanes == h shift of 2
    for (int si = 1; si < 16; ++si) {
#pragma unroll
        for (int c = 0; c < 32; ++c) nb[c] = __shfl(nb[c], src, 64);
        float d0 = 0.f, d1 = 0.f, d2 = 0.f, d3 = 0.f;
#pragma unroll
        for (int c = 0; c < 32; c += 4) {
            d0 += fabsf(col[c+0] - nb[c+0]);
            d1 += fabsf(col[c+1] - nb[c+1]);
            d2 += fabsf(col[c+2] - nb[c+2]);
            d3 += fabsf(col[c+3] - nb[c+3]);
        }
        float ds = (d0 + d1) + (d2 + d3);
        bool cmp;
        bool border = fabs((double)ds - thr) < BORDER;
        if (__ballot(border)) {
            double d64 = 0.0;
#pragma unroll
            for (int c = 0; c < 32; ++c) d64 += fabs((double)col[c] - (double)nb[c]);
            cmp = d64 < thr;
        } else {
            cmp = ((double)ds < thr);
        }
#pragma unroll
        for (int c = 0; c < 32; ++c) Mv[c] = (cmp && nb[c] > Mv[c]) ? nb[c] : Mv[c];
    }
#pragma unroll
    for (int c = 0; c < 32; ++c) {
        float prev = mbase[c * DHW_];
        mbase[c * DHW_] = fmaxf(prev, Mv[c]);
    }
}

// ---------------- axis pass along D: wave = 2 lines (w0, w0+1); lane = d*2 + wsub ----------------
__global__ __launch_bounds__(256) void k_pass_d(const float* __restrict__ x, const double* __restrict__ acc,
                                                float* __restrict__ M) {
    int wv = blockIdx.x * 4 + (threadIdx.x >> 6);   // 0..2047
    int ln = threadIdx.x & 63;
    int b = wv >> 10;
    int r = wv & 1023;
    int h = r >> 5;
    int w0 = (r & 31) * 2;
    int d = ln >> 1, wsub = ln & 1;
    double thr = get_thr(acc, b);
    size_t off = (size_t)b * CDHW_ + d * HW_ + h * W_ + w0 + wsub;
    const float* base = x + off;
    float* mbase = M + off;
    float col[32], nb[32], Mv[32];
#pragma unroll
    for (int c = 0; c < 32; ++c) col[c] = base[c * DHW_];
    bool sel0 = (0.0 < thr);
#pragma unroll
    for (int c = 0; c < 32; ++c) { nb[c] = col[c]; Mv[c] = sel0 ? col[c] : NEG_INF_F; }
    int src = (ln - 4) & 63;                        // rotate by 4 lanes == d shift of 2
    for (int si = 1; si < 16; ++si) {
#pragma unroll
        for (int c = 0; c < 32; ++c) nb[c] = __shfl(nb[c], src, 64);
        float d0 = 0.f, d1 = 0.f, d2 = 0.f, d3 = 0.f;
#pragma unroll
        for (int c = 0; c < 32; c += 4) {
            d0 += fabsf(col[c+0] - nb[c+0]);
            d1 += fabsf(col[c+1] - nb[c+1]);
            d2 += fabsf(col[c+2] - nb[c+2]);
            d3 += fabsf(col[c+3] - nb[c+3]);
        }
        float ds = (d0 + d1) + (d2 + d3);
        bool cmp;
        bool border = fabs((double)ds - thr) < BORDER;
        if (__ballot(border)) {
            double d64 = 0.0;
#pragma unroll
            for (int c = 0; c < 32; ++c) d64 += fabs((double)col[c] - (double)nb[c]);
            cmp = d64 < thr;
        } else {
            cmp = ((double)ds < thr);
        }
#pragma unroll
        for (int c = 0; c < 32; ++c) Mv[c] = (cmp && nb[c] > Mv[c]) ? nb[c] : Mv[c];
    }
#pragma unroll
    for (int c = 0; c < 32; ++c) {
        float prev = mbase[c * DHW_];
        mbase[c * DHW_] = fmaxf(prev, Mv[c]);
    }
}

// ---------------- 1x1x1 conv (64 -> 32) + per-channel batch stats ----------------
__global__ __launch_bounds__(256) void k_conv(const float* __restrict__ x, const float* __restrict__ M,
                                              const float* __restrict__ w, const float* __restrict__ bias,
                                              float* __restrict__ y, double* __restrict__ acc) {
    int idx = blockIdx.x * 256 + threadIdx.x;       // 0..131071 spatial points
    int b = idx >> 16, p = idx & 65535;
    const float* xb = x + (size_t)b * CDHW_ + p;
    const float* mb = M + (size_t)b * CDHW_ + p;
    float z[64];
#pragma unroll
    for (int c = 0; c < 32; ++c) {
        float xv = xb[c * DHW_];
        z[c] = xv;
        float xj = mb[c * DHW_] - xv;               // M - x (M = -inf if nothing selected)
        z[32 + c] = xj > 0.f ? xj : 0.f;
    }
    __shared__ float ytile[256][33];
    float* yout = y + (size_t)b * CDHW_ + p;        // [b][o][p], OC==C
    for (int o = 0; o < 32; ++o) {
        float a = bias[o];
#pragma unroll
        for (int c = 0; c < 64; ++c) a = fmaf(w[o * 64 + c], z[c], a);
        yout[o * DHW_] = a;
        ytile[threadIdx.x][o] = a;
    }
    __syncthreads();
    int o = threadIdx.x & 31, seg = threadIdx.x >> 5;
    float ps = 0.f, pq = 0.f;
#pragma unroll
    for (int j = 0; j < 32; ++j) {
        float v = ytile[seg * 32 + j][o];
        ps += v; pq += v * v;
    }
    __shared__ float psum[8][32], psq[8][32];
    psum[seg][o] = ps; psq[seg][o] = pq;
    __syncthreads();
    if (threadIdx.x < 32) {
        double ts = 0.0, tq = 0.0;
#pragma unroll
        for (int s2 = 0; s2 < 8; ++s2) { ts += (double)psum[s2][threadIdx.x]; tq += (double)psq[s2][threadIdx.x]; }
        atomicAdd(&acc[4 + threadIdx.x], ts);
        atomicAdd(&acc[36 + threadIdx.x], tq);
    }
}

// ---------------- BN normalize (training stats, biased var) + exact GELU, in-place ----------------
__global__ __launch_bounds__(256) void k_out(float* __restrict__ y, const double* __restrict__ acc,
                                             const float* __restrict__ gamma, const float* __restrict__ beta) {
    int idx = blockIdx.x * 256 + threadIdx.x;       // over 1,048,576 float4
    int elem = idx << 2;
    int o = (elem >> 16) & 31;
    double mu = acc[4 + o] / (double)BN_N_;
    double var = acc[36 + o] / (double)BN_N_ - mu * mu;
    float rstd = (float)(1.0 / sqrt(var + 1e-5));
    float mu_f = (float)mu;
    float g = gamma[o], be = beta[o];
    float4 v = ((const float4*)y)[idx];
    float* vv = (float*)&v;
#pragma unroll
    for (int j = 0; j < 4; ++j) {
        float t = (vv[j] - mu_f) * rstd * g + be;
        vv[j] = 0.5f * t * (1.f + erff(t * 0.70710678118654752f));
    }
    ((float4*)y)[idx] = v;
}

extern "C" void kernel_launch(void* const* d_in, const int* in_sizes, int n_in,
                              void* d_out, int out_size, void* d_ws, size_t ws_size,
                              hipStream_t stream) {
    const float* x     = (const float*)d_in[0];
    const float* w     = (const float*)d_in[1];
    const float* bias  = (const float*)d_in[2];
    const float* gamma = (const float*)d_in[3];
    const float* beta  = (const float*)d_in[4];
    float* out = (float*)d_out;
    float* M   = (float*)d_ws;
    double* acc = (double*)((char*)d_ws + ACC_OFF);

    hipMemsetAsync(acc, 0, 68 * sizeof(double), stream);     // zero f64 accumulators every call
    k_norm  <<<512, 256, 0, stream>>>(x, acc);
    k_pass_w<<<512, 256, 0, stream>>>(x, acc, M);
    k_pass_h<<<512, 256, 0, stream>>>(x, acc, M);
    k_pass_d<<<512, 256, 0, stream>>>(x, acc, M);
    k_conv  <<<512, 256, 0, stream>>>(x, M, w, bias, out, acc);
    k_out   <<<4096, 256, 0, stream>>>(out, acc, gamma, beta);
}